// Round 10
// baseline (334.105 us; speedup 1.0000x reference)
//
#include <hip/hip_runtime.h>
#include <math.h>

// GumbelQuantizer: out[n,g,:] = emb[argmax_c(logits[n,g,c] + gumbels[n,g,c])]
// (straight-through forward == hard one-hot; softmax/TAU are argmax-invariant).
// fp16-MFMA fast path + margin-flagged fp64 exact refine for near-ties.
// R10: R9 + lgkmcnt(0) in PIPE_SYNC. R9's race: MFMAs (register-only) sink past
// the volatile-asm wait (rule #18 mechanism), so a wave could cross the barrier
// with iter t-1 ds_reads IN FLIGHT while another wave stages into that same
// buffer ((t+2)%3 == (t-1)%3). Draining lgkmcnt before s_barrier restores the
// exact __syncthreads invariant minus the vmcnt(0) drain (the point of T4).

#define NTOK   32768   // BS*L
#define DIM    512
#define INNER  1024
#define NC     320
#define NGRP   2
#define VD     128
#define OUTD   256
#define RCAP   2048
#define MARGIN 8.0e-3f

// ---- new-path ws layout (bytes) ----
#define L_LIST 16u
#define L_W1T  (64u<<10)
#define L_W2T  (2u<<20)
#define L_XH   (4u<<20)
#define L_H    (36u<<20)
#define L_PART (100u<<20)
#define L_HDW  (104u<<20)
#define WS_NEED (120u<<20)

// ---- fallback (R5) ws layout ----
#define W1F_OFF (1u<<20)
#define W2F_OFF (1u<<21)
#define SMEM_BYTES (65536 + 3328)

typedef _Float16 half8 __attribute__((ext_vector_type(8)));
typedef _Float16 half4 __attribute__((ext_vector_type(4)));
typedef float    f32x4 __attribute__((ext_vector_type(4)));

__device__ __forceinline__ float gelu_f(float s) {
  return 0.5f * s * (1.0f + erff(s * 0.70710678118654752440f));
}

#if defined(__has_builtin) && __has_builtin(__builtin_amdgcn_global_load_lds)
#define GLOAD16(gp, ldsbase) \
  __builtin_amdgcn_global_load_lds((const __attribute__((address_space(1))) void*)(gp), \
                                   (__attribute__((address_space(3))) void*)(ldsbase), 16, 0, 0)
#else
#define GLOAD16(gp, ldsbase) \
  do { *(uint4*)((char*)(ldsbase) + (threadIdx.x & 63) * 16) = *(const uint4*)(gp); } while (0)
#endif

// fenced wait: counted vmcnt + FULL lgkmcnt drain (ds_reads must complete
// before the barrier — MFMAs can sink past volatile asm, ds_reads cannot),
// then barrier, with sched fences pinning both sides.
#define PIPE_SYNC(N) do { \
    __builtin_amdgcn_sched_barrier(0); \
    asm volatile("s_waitcnt vmcnt(" #N ") lgkmcnt(0)" ::: "memory"); \
    __builtin_amdgcn_s_barrier(); \
    __builtin_amdgcn_sched_barrier(0); \
  } while (0)

// ================================================================ K0: prep
#define XH_JOBS   2097152
#define W1T_JOBS  65536
#define W2T_JOBS  81920
#define PREP_JOBS (XH_JOBS + W1T_JOBS + W2T_JOBS)
__global__ __launch_bounds__(256)
void prep2_kernel(const float* __restrict__ x, const float* __restrict__ W1,
                  const float* __restrict__ W2, _Float16* __restrict__ xh,
                  _Float16* __restrict__ W1T, _Float16* __restrict__ W2T,
                  unsigned* __restrict__ cnt) {
  const int o = blockIdx.x * 256 + threadIdx.x;
  if (o == 0) cnt[0] = 0u;
  if (o < XH_JOBS) {
    const float4 v0 = *(const float4*)(x + (size_t)o * 8);
    const float4 v1 = *(const float4*)(x + (size_t)o * 8 + 4);
    half8 hv;
    hv[0] = (_Float16)v0.x; hv[1] = (_Float16)v0.y; hv[2] = (_Float16)v0.z; hv[3] = (_Float16)v0.w;
    hv[4] = (_Float16)v1.x; hv[5] = (_Float16)v1.y; hv[6] = (_Float16)v1.z; hv[7] = (_Float16)v1.w;
    *(half8*)(xh + (size_t)o * 8) = hv;
  } else if (o < XH_JOBS + W1T_JOBS) {
    const int q = o - XH_JOBS;
    const int i = q >> 6, k0 = (q & 63) * 8;
#pragma unroll
    for (int j = 0; j < 8; ++j)
      W1T[(size_t)i * DIM + k0 + j] = (_Float16)W1[(size_t)(k0 + j) * INNER + i];
  } else if (o < PREP_JOBS) {
    const int q = o - XH_JOBS - W1T_JOBS;
    const int c = q >> 7, i0 = (q & 127) * 8;
#pragma unroll
    for (int j = 0; j < 8; ++j)
      W2T[(size_t)c * INNER + i0 + j] = (_Float16)W2[(size_t)(i0 + j) * (NC * NGRP) + c];
  }
}

// per-stage: each wave stages 4x 1KB (its two 16-row chunks of A and of B).
#define STAGE_P(bufbase, ks) do { \
    char* b_ = (bufbase); \
    GLOAD16(gA0 + (ks) * 32, b_ + (w * 2 + 0) * 1024); \
    GLOAD16(gA1 + (ks) * 32, b_ + (w * 2 + 1) * 1024); \
    GLOAD16(gB0 + (ks) * 32, b_ + 8192 + (w * 2 + 0) * 1024); \
    GLOAD16(gB1 + (ks) * 32, b_ + 8192 + (w * 2 + 1) * 1024); \
  } while (0)

// ================================================================ K1: GEMM1
// h = gelu(xh @ W1 + b1), fp16 [32768][1024]. 128x128, BK=32, 256 thr, 3-buf.
__global__ __launch_bounds__(256, 4)
void gemm1_kernel(const _Float16* __restrict__ xh, const _Float16* __restrict__ W1T,
                  const float* __restrict__ b1, _Float16* __restrict__ h) {
  __shared__ char smem[49152];
  const int tid = threadIdx.x;
  const int w = tid >> 6, l = tid & 63;
  const int l15 = l & 15, lq = l >> 4;
  const int bid = blockIdx.x;
  const int xcd = bid & 7, j = bid >> 3;            // 2048 = 8 * 256
  const int bm = xcd * 32 + (j >> 3), bn = j & 7;
  const int wm = w >> 1, wn = w & 1;

  const int r0 = (w * 2 + 0) * 16 + (l >> 2);
  const int r1 = (w * 2 + 1) * 16 + (l >> 2);
  const int c0 = (((l & 3) ^ (r0 & 3)) * 8);
  const int c1 = (((l & 3) ^ (r1 & 3)) * 8);
  const _Float16* gA0 = xh  + (size_t)(bm * 128 + r0) * DIM + c0;
  const _Float16* gA1 = xh  + (size_t)(bm * 128 + r1) * DIM + c1;
  const _Float16* gB0 = W1T + (size_t)(bn * 128 + r0) * DIM + c0;
  const _Float16* gB1 = W1T + (size_t)(bn * 128 + r1) * DIM + c1;

  f32x4 acc[4][4];
#pragma unroll
  for (int i = 0; i < 4; ++i)
#pragma unroll
    for (int jj = 0; jj < 4; ++jj) { f32x4 z = {0.f, 0.f, 0.f, 0.f}; acc[i][jj] = z; }

  const int swz = (lq ^ (l15 & 3)) << 4;
  const int aoff = (wm * 64 + l15) * 64 + swz;
  const int boff = 8192 + (wn * 64 + l15) * 64 + swz;

  STAGE_P(smem, 0);
  asm volatile("" ::: "memory");                    // pin issue order: S0 before S1
  STAGE_P(smem + 16384, 1);
  for (int ks = 0; ks < 16; ++ks) {
    if (ks + 1 < 16) PIPE_SYNC(4); else PIPE_SYNC(0);
    if (ks + 2 < 16) STAGE_P(smem + ((ks + 2) % 3) * 16384, ks + 2);
    const char* base = smem + (ks % 3) * 16384;
    half8 a[4], b[4];
#pragma unroll
    for (int mi = 0; mi < 4; ++mi) a[mi] = *(const half8*)(base + aoff + mi * 1024);
#pragma unroll
    for (int ni = 0; ni < 4; ++ni) b[ni] = *(const half8*)(base + boff + ni * 1024);
#pragma unroll
    for (int mi = 0; mi < 4; ++mi)
#pragma unroll
      for (int ni = 0; ni < 4; ++ni)
        acc[mi][ni] = __builtin_amdgcn_mfma_f32_16x16x32_f16(a[mi], b[ni], acc[mi][ni], 0, 0, 0);
  }
  asm volatile("s_waitcnt vmcnt(0) lgkmcnt(0)" ::: "memory");
  __syncthreads();

  // epilogue: +b1, GELU, fp16 -> eT (col XOR-swizzled by lq), coalesced store
  _Float16* eT = (_Float16*)smem;
  float bb[4];
#pragma unroll
  for (int ni = 0; ni < 4; ++ni) bb[ni] = b1[bn * 128 + wn * 64 + ni * 16 + l15];
#pragma unroll
  for (int mi = 0; mi < 4; ++mi) {
    const int row = wm * 64 + mi * 16 + lq * 4;
#pragma unroll
    for (int ni = 0; ni < 4; ++ni) {
      const int col = (wn * 64 + ni * 16 + l15) ^ (lq << 4);  // (row>>2)&3 == lq
#pragma unroll
      for (int r = 0; r < 4; ++r)
        eT[(row + r) * 128 + col] = (_Float16)gelu_f(acc[mi][ni][r] + bb[ni]);
    }
  }
  __syncthreads();
#pragma unroll
  for (int it = 0; it < 8; ++it) {
    const int s = tid + it * 256;
    const int row = s >> 4, i8 = s & 15;
    const int colp = (i8 * 8) ^ (((row >> 2) & 3) << 4);
    *(half8*)(h + (size_t)(bm * 128 + row) * INNER + bn * 128 + i8 * 8)
        = *(const half8*)(eT + row * 128 + colp);
  }
}

// ================================================================ K2: GEMM2
// logits = h @ W2 + b2 + gum; per-(token,slot) top-2 partials.
__global__ __launch_bounds__(256, 4)
void gemm2_kernel(const _Float16* __restrict__ h, const _Float16* __restrict__ W2T,
                  const float* __restrict__ b2, const float* __restrict__ gum,
                  unsigned* __restrict__ part) {
  __shared__ char smem[49152];
  const int tid = threadIdx.x;
  const int w = tid >> 6, l = tid & 63;
  const int l15 = l & 15, lq = l >> 4;
  const int bid = blockIdx.x;
  const int xcd = bid & 7, j = bid >> 3;            // 1280 = 8 * 160
  const int bm = xcd * 32 + j / 5, bt = j % 5;
  const int wm = w >> 1, wn = w & 1;

  const int r0 = (w * 2 + 0) * 16 + (l >> 2);
  const int r1 = (w * 2 + 1) * 16 + (l >> 2);
  const int c0 = (((l & 3) ^ (r0 & 3)) * 8);
  const int c1 = (((l & 3) ^ (r1 & 3)) * 8);
  const _Float16* gA0 = h   + (size_t)(bm * 128 + r0) * INNER + c0;
  const _Float16* gA1 = h   + (size_t)(bm * 128 + r1) * INNER + c1;
  const _Float16* gB0 = W2T + (size_t)(bt * 128 + r0) * INNER + c0;
  const _Float16* gB1 = W2T + (size_t)(bt * 128 + r1) * INNER + c1;

  f32x4 acc[4][4];
#pragma unroll
  for (int i = 0; i < 4; ++i)
#pragma unroll
    for (int jj = 0; jj < 4; ++jj) { f32x4 z = {0.f, 0.f, 0.f, 0.f}; acc[i][jj] = z; }

  const int swz = (lq ^ (l15 & 3)) << 4;
  const int aoff = (wm * 64 + l15) * 64 + swz;
  const int boff = 8192 + (wn * 64 + l15) * 64 + swz;

  STAGE_P(smem, 0);
  asm volatile("" ::: "memory");                    // pin issue order: S0 before S1
  STAGE_P(smem + 16384, 1);
  for (int ks = 0; ks < 32; ++ks) {
    if (ks + 1 < 32) PIPE_SYNC(4); else PIPE_SYNC(0);
    if (ks + 2 < 32) STAGE_P(smem + ((ks + 2) % 3) * 16384, ks + 2);
    const char* base = smem + (ks % 3) * 16384;
    half8 a[4], b[4];
#pragma unroll
    for (int mi = 0; mi < 4; ++mi) a[mi] = *(const half8*)(base + aoff + mi * 1024);
#pragma unroll
    for (int ni = 0; ni < 4; ++ni) b[ni] = *(const half8*)(base + boff + ni * 1024);
#pragma unroll
    for (int mi = 0; mi < 4; ++mi)
#pragma unroll
      for (int ni = 0; ni < 4; ++ni)
        acc[mi][ni] = __builtin_amdgcn_mfma_f32_16x16x32_f16(a[mi], b[ni], acc[mi][ni], 0, 0, 0);
  }
  asm volatile("s_waitcnt vmcnt(0) lgkmcnt(0)" ::: "memory");

  // epilogue in two halves (f32 eF[64][128], col XOR-swizzled by lq&1)
  float* eF = (float*)smem;
  const int nm = (bt == 2) ? 8 : 16;
#pragma unroll
  for (int half = 0; half < 2; ++half) {
    __syncthreads();
    if (wm == half) {
#pragma unroll
      for (int mi = 0; mi < 4; ++mi) {
        const int rl = mi * 16 + lq * 4;
#pragma unroll
        for (int ni = 0; ni < 4; ++ni) {
          const int col = (wn * 64 + ni * 16 + l15) ^ ((lq & 1) << 4);  // (rl>>2)&1 == lq&1
#pragma unroll
          for (int r = 0; r < 4; ++r) eF[(rl + r) * 128 + col] = acc[mi][ni][r];
        }
      }
    }
    __syncthreads();
#pragma unroll
    for (int it = 0; it < 8; ++it) {
      const int s = tid + it * 256;
      const int rl = s >> 5, cc = (s & 31) * 4;
      const int ccp = cc ^ (((rl >> 2) & 1) << 4);
      const int t = bm * 128 + half * 64 + rl;
      const float4 lv  = *(const float4*)(eF + rl * 128 + ccp);
      const float4 b2v = *(const float4*)(b2 + bt * 128 + cc);
      const float4 gv  = *(const float4*)(gum + (size_t)t * 640 + bt * 128 + cc);
      float m1 = -1e30f, m2 = -1e30f; unsigned i1 = 0;
      const float vv[4] = {(lv.x + b2v.x) + gv.x, (lv.y + b2v.y) + gv.y,
                           (lv.z + b2v.z) + gv.z, (lv.w + b2v.w) + gv.w};
#pragma unroll
      for (int r = 0; r < 4; ++r) {
        const unsigned c = (unsigned)(bt * 128 + cc + r);
        if (vv[r] > m1) { m2 = m1; m1 = vv[r]; i1 = c; }
        else if (vv[r] > m2) m2 = vv[r];
      }
      for (int m = 1; m <= nm; m <<= 1) {
        const float om1 = __shfl_xor(m1, m);
        const float om2 = __shfl_xor(m2, m);
        const unsigned oi = (unsigned)__shfl_xor((int)i1, m);
        const bool take = (om1 > m1) || (om1 == m1 && oi < i1);
        if (take) { m2 = fmaxf(m1, om2); m1 = om1; i1 = oi; }
        else      { m2 = fmaxf(m2, om1); }
      }
      const int lr = tid & 31;
      const bool writer = (bt == 2) ? (lr == 0 || lr == 16) : (lr == 0);
      if (writer) {
        int slot;
        if (bt == 0) slot = 0; else if (bt == 1) slot = 1;
        else if (bt == 3) slot = 4; else if (bt == 4) slot = 5;
        else slot = (i1 < (unsigned)NC) ? 2 : 3;
        const unsigned ing = (i1 < (unsigned)NC) ? i1 : (i1 - NC);
        unsigned* p = part + ((size_t)t * 6 + slot) * 4;
        p[0] = __float_as_uint(m1);
        p[1] = __float_as_uint(m2);
        p[2] = ing;
      }
    }
  }
}

// ================================================================ K3: combine + gather
__global__ __launch_bounds__(256, 4)
void reduce_kernel(const unsigned* __restrict__ part, const float* __restrict__ emb,
                   float* __restrict__ out, unsigned* __restrict__ cnt,
                   unsigned* __restrict__ list) {
  __shared__ unsigned idxs[256];
  const int tid = threadIdx.x;
  const int pair = blockIdx.x * 256 + tid;
  const int t = pair >> 1, g = pair & 1;
  float m1 = -1e30f, m2 = -1e30f; unsigned i1 = 0;
#pragma unroll
  for (int s = 0; s < 3; ++s) {
    const unsigned* p = part + ((size_t)t * 6 + g * 3 + s) * 4;
    const float a1 = __uint_as_float(p[0]);
    const float a2 = __uint_as_float(p[1]);
    const unsigned ai = p[2];
    if (a1 > m1) { m2 = fmaxf(m1, a2); m1 = a1; i1 = ai; }
    else         { m2 = fmaxf(m2, a1); }
  }
  idxs[tid] = i1;
  if (m1 - m2 < MARGIN) {
    const unsigned pos = atomicAdd(cnt, 1u);
    if (pos < RCAP) list[pos] = (unsigned)((t << 1) | g);
  }
  __syncthreads();
#pragma unroll
  for (int it = 0; it < 32; ++it) {
    const int s2 = tid + it * 256;
    const int p = s2 >> 5, dd = (s2 & 31) * 4;
    *(float4*)(out + (size_t)blockIdx.x * 32768 + p * 128 + dd)
        = *(const float4*)(emb + (size_t)idxs[p] * VD + dd);
  }
}

// ================================================================ refine (unchanged)
__global__ __launch_bounds__(512, 4)
void refine1_kernel(const float* __restrict__ x, const float* __restrict__ W1,
                    const float* __restrict__ b1,
                    const unsigned* __restrict__ cnt, const unsigned* __restrict__ list,
                    float* __restrict__ hdws) {
  __shared__ float xs[DIM];
  unsigned n = cnt[0]; if (n > RCAP) n = RCAP;
  const unsigned e = blockIdx.x;
  if (e >= n) return;
  const unsigned tok = list[e] >> 1;
  const int tid = threadIdx.x;
  xs[tid] = x[(size_t)tok * DIM + tid];
  __syncthreads();
  double a0 = 0.0, a1 = 0.0, c0 = 0.0, c1 = 0.0;
#pragma unroll 4
  for (int k = 0; k < DIM; k += 2) {
    const double x0 = (double)xs[k], x1 = (double)xs[k + 1];
    const float* rr0 = W1 + (size_t)k * INNER + tid;
    const float* rr1 = W1 + (size_t)(k + 1) * INNER + tid;
    a0 += x0 * (double)rr0[0];
    a1 += x0 * (double)rr0[512];
    c0 += x1 * (double)rr1[0];
    c1 += x1 * (double)rr1[512];
  }
  const double s0 = a0 + c0 + (double)b1[tid];
  const double s1 = a1 + c1 + (double)b1[tid + 512];
  hdws[(size_t)e * INNER + tid]       = (float)(0.5 * s0 * (1.0 + erf(s0 * 0.70710678118654752440)));
  hdws[(size_t)e * INNER + tid + 512] = (float)(0.5 * s1 * (1.0 + erf(s1 * 0.70710678118654752440)));
}

__global__ __launch_bounds__(320, 4)
void refine2_kernel(const float* __restrict__ gum, const float* __restrict__ W2,
                    const float* __restrict__ b2, const float* __restrict__ emb,
                    float* __restrict__ out,
                    const unsigned* __restrict__ cnt, const unsigned* __restrict__ list,
                    const float* __restrict__ hdws) {
  __shared__ float hs[INNER];
  __shared__ double wv[5];
  __shared__ int wi[5];
  __shared__ int best;
  unsigned n = cnt[0]; if (n > RCAP) n = RCAP;
  const unsigned e = blockIdx.x;
  if (e >= n) return;
  const unsigned tok = list[e] >> 1;
  const int g = (int)(list[e] & 1u);
  const int tid = threadIdx.x;
  for (int j = tid; j < INNER; j += 320) hs[j] = hdws[(size_t)e * INNER + j];
  __syncthreads();
  const float* w2c = W2 + (size_t)g * NC + tid;
  double acc = 0.0, accb = 0.0;
#pragma unroll 4
  for (int k = 0; k < INNER; k += 2) {
    acc  += (double)hs[k]     * (double)w2c[(size_t)k * (NC * NGRP)];
    accb += (double)hs[k + 1] * (double)w2c[(size_t)(k + 1) * (NC * NGRP)];
  }
  double v = acc + accb + (double)b2[g * NC + tid]
                        + (double)gum[((size_t)tok * 2 + g) * NC + tid];
  int bi = tid;
#pragma unroll
  for (int m = 1; m < 64; m <<= 1) {
    const double ov = __shfl_xor(v, m);
    const int oi = __shfl_xor(bi, m);
    if (ov > v || (ov == v && oi < bi)) { v = ov; bi = oi; }
  }
  if ((tid & 63) == 0) { wv[tid >> 6] = v; wi[tid >> 6] = bi; }
  __syncthreads();
  if (tid == 0) {
    double bv = wv[0]; int bb = wi[0];
#pragma unroll
    for (int k = 1; k < 5; ++k)
      if (wv[k] > bv || (wv[k] == bv && wi[k] < bb)) { bv = wv[k]; bb = wi[k]; }
    best = bb;
  }
  __syncthreads();
  if (tid < VD)
    out[(size_t)tok * OUTD + g * VD + tid] = emb[(size_t)best * VD + tid];
}

// ================================================================ FALLBACK (R5 path)
#define W1F_N (16 * 64 * 64)
#define W2F_N (32 * 40 * 64)
__global__ void prep_kernel(const float* __restrict__ W1, const float* __restrict__ W2,
                            _Float16* __restrict__ W1F, _Float16* __restrict__ W2F,
                            unsigned* __restrict__ cnt) {
  const int o = blockIdx.x * 256 + threadIdx.x;
  if (o == 0) cnt[0] = 0u;
  if (o < W1F_N) {
    const int l = o & 63, ib = (o >> 6) & 63, ks = o >> 12;
    const int inner = ib * 16 + (l & 15);
    const int kb = ks * 32 + (l >> 4) * 8;
    _Float16* d = W1F + (size_t)o * 8;
#pragma unroll
    for (int j = 0; j < 8; ++j) d[j] = (_Float16)W1[(size_t)(kb + j) * INNER + inner];
  } else {
    const int o2 = o - W1F_N;
    if (o2 < W2F_N) {
      const int l = o2 & 63, cb = (o2 >> 6) % 40, ks = o2 / (40 * 64);
      const int code = cb * 16 + (l & 15);
      const int kb = ks * 32 + (l >> 4) * 8;
      _Float16* d = W2F + (size_t)o2 * 8;
#pragma unroll
      for (int j = 0; j < 8; ++j) d[j] = (_Float16)W2[(size_t)(kb + j) * (NC * NGRP) + code];
    }
  }
}

__global__ __launch_bounds__(512, 4)
void fused_kernel(const float* __restrict__ x, const float* __restrict__ gum,
                  const _Float16* __restrict__ W1F, const _Float16* __restrict__ W2F,
                  const float* __restrict__ b1, const float* __restrict__ b2,
                  const float* __restrict__ emb, float* __restrict__ out,
                  unsigned* __restrict__ cnt, unsigned* __restrict__ list) {
  extern __shared__ char smem[];
  float*    redm1 = (float*)(smem + 65536);
  float*    redm2 = (float*)(smem + 65536 + 1024);
  unsigned* redi  = (unsigned*)(smem + 65536 + 2048);
  unsigned* idxs  = (unsigned*)(smem + 65536 + 3072);
  const int tid = threadIdx.x;
  const int w = tid >> 6, l = tid & 63;
  const int l15 = l & 15, lq = l >> 4;
  const int T0 = blockIdx.x << 5;
#pragma unroll
  for (int i = 0; i < 8; ++i) {
    const int q = tid + i * 512;
    const int row = q >> 7;
    const int c = (q & 127) << 2;
    const float4 v = *(const float4*)(x + (size_t)(T0 + row) * DIM + c);
    half4 hv; hv[0] = (_Float16)v.x; hv[1] = (_Float16)v.y;
    hv[2] = (_Float16)v.z; hv[3] = (_Float16)v.w;
    const unsigned byte = ((unsigned)(row * 1024 + c * 2)) ^ ((unsigned)(row & 7) << 4);
    *(half4*)(smem + byte) = hv;
  }
  __syncthreads();
  {
    f32x4 acc[8][2];
#pragma unroll
    for (int i = 0; i < 8; ++i)
#pragma unroll
      for (int jj = 0; jj < 2; ++jj) { f32x4 z = {0.f,0.f,0.f,0.f}; acc[i][jj] = z; }
    const _Float16* w1f = W1F + (size_t)(w * 8) * 512 + (size_t)l * 8;
    for (int ks = 0; ks < 16; ++ks) {
      const int k0 = ks * 32;
      half8 a[8], bf[2];
#pragma unroll
      for (int mt = 0; mt < 8; ++mt) a[mt] = *(const half8*)(w1f + (size_t)(ks * 64 + mt) * 512);
#pragma unroll
      for (int nt = 0; nt < 2; ++nt) {
        const int token = nt * 16 + l15;
        const unsigned byte = ((unsigned)(token * 1024 + (k0 + lq * 8) * 2))
                              ^ ((unsigned)(token & 7) << 4);
        bf[nt] = *(const half8*)(smem + byte);
      }
#pragma unroll
      for (int mt = 0; mt < 8; ++mt)
#pragma unroll
        for (int nt = 0; nt < 2; ++nt)
          acc[mt][nt] = __builtin_amdgcn_mfma_f32_16x16x32_f16(a[mt], bf[nt], acc[mt][nt], 0, 0, 0);
    }
    __syncthreads();
#pragma unroll
    for (int mt = 0; mt < 8; ++mt) {
      const int inner0 = w * 128 + mt * 16 + lq * 4;
      const float4 bv = *(const float4*)(b1 + inner0);
#pragma unroll
      for (int nt = 0; nt < 2; ++nt) {
        const int token = nt * 16 + l15;
        const f32x4 v = acc[mt][nt];
        half4 hv;
        hv[0] = (_Float16)gelu_f(v[0] + bv.x);
        hv[1] = (_Float16)gelu_f(v[1] + bv.y);
        hv[2] = (_Float16)gelu_f(v[2] + bv.z);
        hv[3] = (_Float16)gelu_f(v[3] + bv.w);
        const unsigned byte = ((unsigned)(token * 2048 + inner0 * 2))
                              ^ ((unsigned)(token & 7) << 4);
        *(half4*)(smem + byte) = hv;
      }
    }
  }
  __syncthreads();
  const int g = w >> 2;
  {
    f32x4 acc[5][2];
#pragma unroll
    for (int i = 0; i < 5; ++i)
#pragma unroll
      for (int jj = 0; jj < 2; ++jj) { f32x4 z = {0.f,0.f,0.f,0.f}; acc[i][jj] = z; }
    const _Float16* w2f = W2F + (size_t)(w * 5) * 512 + (size_t)l * 8;
    for (int ks = 0; ks < 32; ++ks) {
      const int k0 = ks * 32;
      half8 a[5], bf[2];
#pragma unroll
      for (int mt = 0; mt < 5; ++mt) a[mt] = *(const half8*)(w2f + (size_t)(ks * 40 + mt) * 512);
#pragma unroll
      for (int nt = 0; nt < 2; ++nt) {
        const int token = nt * 16 + l15;
        const unsigned byte = ((unsigned)(token * 2048 + (k0 + lq * 8) * 2))
                              ^ ((unsigned)(token & 7) << 4);
        bf[nt] = *(const half8*)(smem + byte);
      }
#pragma unroll
      for (int mt = 0; mt < 5; ++mt)
#pragma unroll
        for (int nt = 0; nt < 2; ++nt)
          acc[mt][nt] = __builtin_amdgcn_mfma_f32_16x16x32_f16(a[mt], bf[nt], acc[mt][nt], 0, 0, 0);
    }
    float m1v[2] = {-1e30f,-1e30f};
    float m2v[2] = {-1e30f,-1e30f};
    unsigned i1v[2] = {0,0};
#pragma unroll
    for (int mt = 0; mt < 5; ++mt) {
      const int code0 = w * 80 + mt * 16 + lq * 4;
      const int cg0 = code0 - g * NC;
      const float4 b2v = *(const float4*)(b2 + code0);
#pragma unroll
      for (int nt = 0; nt < 2; ++nt) {
        const int tokg = T0 + nt * 16 + l15;
        const float4 gv = *(const float4*)(gum + ((size_t)tokg * 2 + g) * NC + cg0);
        const f32x4 v = acc[mt][nt];
        const float ss[4] = {v[0] + b2v.x + gv.x, v[1] + b2v.y + gv.y,
                             v[2] + b2v.z + gv.z, v[3] + b2v.w + gv.w};
#pragma unroll
        for (int r = 0; r < 4; ++r) {
          const float sv = ss[r];
          const unsigned cc = (unsigned)(cg0 + r);
          if (sv > m1v[nt]) { m2v[nt] = m1v[nt]; m1v[nt] = sv; i1v[nt] = cc; }
          else if (sv > m2v[nt]) m2v[nt] = sv;
        }
      }
    }
#pragma unroll
    for (int mask = 16; mask <= 32; mask <<= 1) {
#pragma unroll
      for (int nt = 0; nt < 2; ++nt) {
        const float om1 = __shfl_xor(m1v[nt], mask);
        const float om2 = __shfl_xor(m2v[nt], mask);
        const unsigned oi = (unsigned)__shfl_xor((int)i1v[nt], mask);
        const bool take = (om1 > m1v[nt]) || (om1 == m1v[nt] && oi < i1v[nt]);
        if (take) { m2v[nt] = fmaxf(m1v[nt], om2); m1v[nt] = om1; i1v[nt] = oi; }
        else      { m2v[nt] = fmaxf(m2v[nt], om1); }
      }
    }
    if (l < 16) {
#pragma unroll
      for (int nt = 0; nt < 2; ++nt) {
        const int tok = nt * 16 + l15;
        redm1[w * 32 + tok] = m1v[nt];
        redm2[w * 32 + tok] = m2v[nt];
        redi [w * 32 + tok] = i1v[nt];
      }
    }
  }
  __syncthreads();
  if (tid < 64) {
    const int pg = tid >> 5;
    const int tok = tid & 31;
    float m1 = -1e30f, m2 = -1e30f; unsigned i1 = 0;
#pragma unroll
    for (int k = 0; k < 4; ++k) {
      const int ww = pg * 4 + k;
      const float a1 = redm1[ww * 32 + tok];
      const float a2 = redm2[ww * 32 + tok];
      const unsigned ai = redi[ww * 32 + tok];
      if (a1 > m1) { m2 = fmaxf(m1, a2); m1 = a1; i1 = ai; }
      else         { m2 = fmaxf(m2, a1); }
    }
    idxs[tid] = i1;
    if (m1 - m2 < MARGIN) {
      const unsigned pos = atomicAdd(cnt, 1u);
      if (pos < RCAP) list[pos] = (unsigned)(((T0 + tok) << 1) | pg);
    }
  }
  __syncthreads();
#pragma unroll
  for (int i = 0; i < 4; ++i) {
    const int q = tid + i * 512;
    const int p = q >> 5;
    const int dd = q & 31;
    const int pg = p >> 5;
    const int tok = p & 31;
    const unsigned idx = idxs[p];
    *(float4*)(out + (size_t)(T0 + tok) * OUTD + pg * VD + dd * 4)
      = *(const float4*)(emb + (size_t)idx * VD + dd * 4);
  }
}

__global__ __launch_bounds__(512, 1)
void refine_kernel(const float* __restrict__ x, const float* __restrict__ gum,
                   const float* __restrict__ W1, const float* __restrict__ b1,
                   const float* __restrict__ W2, const float* __restrict__ b2,
                   const float* __restrict__ emb, float* __restrict__ out,
                   const unsigned* __restrict__ cnt, const unsigned* __restrict__ list) {
  __shared__ double xs[4][DIM];
  __shared__ double hd[4][INNER];
  __shared__ double sc[4][NC];
  __shared__ int amax[4];
  const int tid = threadIdx.x;
  unsigned n = cnt[0];
  if (n > RCAP) n = RCAP;
  for (unsigned base = blockIdx.x * 4u; base < n; base += gridDim.x * 4u) {
    const int nb = (int)((n - base) < 4u ? (n - base) : 4u);
    unsigned ng[4];
#pragma unroll
    for (int e = 0; e < 4; ++e) ng[e] = list[base + (e < nb ? e : 0)];
    for (int e = 0; e < nb; ++e)
      xs[e][tid] = (double)x[(size_t)(ng[e] >> 1) * DIM + tid];
    __syncthreads();
#pragma unroll
    for (int jj = 0; jj < 2; ++jj) {
      const int j = tid + jj * 512;
      double a0 = 0, a1 = 0, a2 = 0, a3 = 0;
      for (int k = 0; k < DIM; ++k) {
        const double wvv = (double)W1[(size_t)k * INNER + j];
        a0 += xs[0][k] * wvv; a1 += xs[1][k] * wvv;
        a2 += xs[2][k] * wvv; a3 += xs[3][k] * wvv;
      }
      const double bb = (double)b1[j];
      const double s0 = a0 + bb, s1 = a1 + bb, s2 = a2 + bb, s3 = a3 + bb;
      hd[0][j] = 0.5 * s0 * (1.0 + erf(s0 * 0.70710678118654752440));
      hd[1][j] = 0.5 * s1 * (1.0 + erf(s1 * 0.70710678118654752440));
      hd[2][j] = 0.5 * s2 * (1.0 + erf(s2 * 0.70710678118654752440));
      hd[3][j] = 0.5 * s3 * (1.0 + erf(s3 * 0.70710678118654752440));
    }
    __syncthreads();
    for (int task = tid; task < 4 * NC; task += 512) {
      const int e = task / NC;
      const int c = task - e * NC;
      if (e < nb) {
        const unsigned tok = ng[e] >> 1;
        const int gg = (int)(ng[e] & 1u);
        const float* w2c = W2 + (size_t)gg * NC + c;
        double acc = 0.0;
        for (int k = 0; k < INNER; ++k)
          acc += hd[e][k] * (double)w2c[(size_t)k * (NC * NGRP)];
        sc[e][c] = acc + (double)b2[gg * NC + c]
                       + (double)gum[((size_t)tok * 2 + gg) * NC + c];
      }
    }
    __syncthreads();
    if (tid < 4 && tid < nb) {
      double bestv = sc[tid][0]; int bi = 0;
      for (int c = 1; c < NC; ++c)
        if (sc[tid][c] > bestv) { bestv = sc[tid][c]; bi = c; }
      amax[tid] = bi;
    }
    __syncthreads();
    {
      const int e = tid >> 7;
      const int d = tid & 127;
      if (e < nb) {
        const unsigned tok = ng[e] >> 1;
        const int gg = (int)(ng[e] & 1u);
        out[(size_t)tok * OUTD + gg * VD + d] = emb[(size_t)amax[e] * VD + d];
      }
    }
    __syncthreads();
  }
}

// ================================================================ launch
extern "C" void kernel_launch(void* const* d_in, const int* in_sizes, int n_in,
                              void* d_out, int out_size, void* d_ws, size_t ws_size,
                              hipStream_t stream) {
  (void)in_sizes; (void)n_in; (void)out_size;
  const float* x   = (const float*)d_in[0];
  const float* gum = (const float*)d_in[1];
  const float* W1  = (const float*)d_in[2];
  const float* b1  = (const float*)d_in[3];
  const float* W2  = (const float*)d_in[4];
  const float* b2  = (const float*)d_in[5];
  const float* emb = (const float*)d_in[6];
  float* out = (float*)d_out;
  char* ws = (char*)d_ws;
  unsigned* cnt  = (unsigned*)ws;
  unsigned* list = (unsigned*)(ws + L_LIST);

  if (ws_size >= (size_t)WS_NEED) {
    _Float16* W1T = (_Float16*)(ws + L_W1T);
    _Float16* W2T = (_Float16*)(ws + L_W2T);
    _Float16* xh  = (_Float16*)(ws + L_XH);
    _Float16* h   = (_Float16*)(ws + L_H);
    unsigned* part = (unsigned*)(ws + L_PART);
    float* hdws = (float*)(ws + L_HDW);

    prep2_kernel<<<(PREP_JOBS + 255) / 256, 256, 0, stream>>>(x, W1, W2, xh, W1T, W2T, cnt);
    gemm1_kernel<<<(NTOK / 128) * 8, 256, 0, stream>>>(xh, W1T, b1, h);
    gemm2_kernel<<<(NTOK / 128) * 5, 256, 0, stream>>>(h, W2T, b2, gum, part);
    reduce_kernel<<<NTOK * NGRP / 256, 256, 0, stream>>>(part, emb, out, cnt, list);
    refine1_kernel<<<RCAP, 512, 0, stream>>>(x, W1, b1, cnt, list, hdws);
    refine2_kernel<<<RCAP, 320, 0, stream>>>(gum, W2, b2, emb, out, cnt, list, hdws);
  } else {
    _Float16* W1F = (_Float16*)(ws + W1F_OFF);
    _Float16* W2F = (_Float16*)(ws + W2F_OFF);
    hipFuncSetAttribute((const void*)fused_kernel,
                        hipFuncAttributeMaxDynamicSharedMemorySize, SMEM_BYTES);
    const int prep_items = W1F_N + W2F_N;
    prep_kernel<<<(prep_items + 255) / 256, 256, 0, stream>>>(W1, W2, W1F, W2F, cnt);
    fused_kernel<<<NTOK / 32, 512, SMEM_BYTES, stream>>>(x, gum, W1F, W2F, b1, b2,
                                                         emb, out, cnt, list);
    refine_kernel<<<256, 512, 0, stream>>>(x, gum, W1, b1, W2, b2, emb, out, cnt, list);
  }
}

// Round 11
// 312.147 us; speedup vs baseline: 1.0703x; 1.0703x over previous
//
#include <hip/hip_runtime.h>
#include <math.h>

// GumbelQuantizer: out[n,g,:] = emb[argmax_c(logits[n,g,c] + gumbels[n,g,c])]
// (straight-through forward == hard one-hot; softmax/TAU are argmax-invariant).
// fp16-MFMA fast path + margin-flagged fp64 exact refine for near-ties.
// R11: depth-2 counted-vmcnt pipeline with TWO buffers (32KB LDS). R10 proved
// the sync discipline (vmcnt(N)+lgkmcnt(0)+s_barrier+sched_barrier) but its
// 3rd buffer (48KB) halved occupancy and regressed. Here: compute buf[t&1],
// then lgkm-drain barrier, then re-stage tile t+2 into the just-freed buffer.
// S(t+1) stays in flight across both barriers -> ~1 full iteration of latency
// coverage at R7's LDS footprint/occupancy.

#define NTOK   32768   // BS*L
#define DIM    512
#define INNER  1024
#define NC     320
#define NGRP   2
#define VD     128
#define OUTD   256
#define RCAP   2048
#define MARGIN 8.0e-3f

// ---- new-path ws layout (bytes) ----
#define L_LIST 16u
#define L_W1T  (64u<<10)
#define L_W2T  (2u<<20)
#define L_XH   (4u<<20)
#define L_H    (36u<<20)
#define L_PART (100u<<20)
#define L_HDW  (104u<<20)
#define WS_NEED (120u<<20)

// ---- fallback (R5) ws layout ----
#define W1F_OFF (1u<<20)
#define W2F_OFF (1u<<21)
#define SMEM_BYTES (65536 + 3328)

typedef _Float16 half8 __attribute__((ext_vector_type(8)));
typedef _Float16 half4 __attribute__((ext_vector_type(4)));
typedef float    f32x4 __attribute__((ext_vector_type(4)));

__device__ __forceinline__ float gelu_f(float s) {
  return 0.5f * s * (1.0f + erff(s * 0.70710678118654752440f));
}

#if defined(__has_builtin) && __has_builtin(__builtin_amdgcn_global_load_lds)
#define GLOAD16(gp, ldsbase) \
  __builtin_amdgcn_global_load_lds((const __attribute__((address_space(1))) void*)(gp), \
                                   (__attribute__((address_space(3))) void*)(ldsbase), 16, 0, 0)
#else
#define GLOAD16(gp, ldsbase) \
  do { *(uint4*)((char*)(ldsbase) + (threadIdx.x & 63) * 16) = *(const uint4*)(gp); } while (0)
#endif

// top sync of iter t: stage-t landed (counted, in-order retire); barrier; fence.
#define PIPE_TOP(N) do { \
    __builtin_amdgcn_sched_barrier(0); \
    asm volatile("s_waitcnt vmcnt(" #N ")" ::: "memory"); \
    __builtin_amdgcn_s_barrier(); \
    __builtin_amdgcn_sched_barrier(0); \
  } while (0)
// bottom sync: all waves' ds_reads of the current buffer complete -> safe to
// overwrite it. (ds_reads cannot cross the "memory" asm; MFMAs may, harmless.)
#define PIPE_BOT() do { \
    __builtin_amdgcn_sched_barrier(0); \
    asm volatile("s_waitcnt lgkmcnt(0)" ::: "memory"); \
    __builtin_amdgcn_s_barrier(); \
    __builtin_amdgcn_sched_barrier(0); \
  } while (0)

// ================================================================ K0: prep
#define XH_JOBS   2097152
#define W1T_JOBS  65536
#define W2T_JOBS  81920
#define PREP_JOBS (XH_JOBS + W1T_JOBS + W2T_JOBS)
__global__ __launch_bounds__(256)
void prep2_kernel(const float* __restrict__ x, const float* __restrict__ W1,
                  const float* __restrict__ W2, _Float16* __restrict__ xh,
                  _Float16* __restrict__ W1T, _Float16* __restrict__ W2T,
                  unsigned* __restrict__ cnt) {
  const int o = blockIdx.x * 256 + threadIdx.x;
  if (o == 0) cnt[0] = 0u;
  if (o < XH_JOBS) {
    const float4 v0 = *(const float4*)(x + (size_t)o * 8);
    const float4 v1 = *(const float4*)(x + (size_t)o * 8 + 4);
    half8 hv;
    hv[0] = (_Float16)v0.x; hv[1] = (_Float16)v0.y; hv[2] = (_Float16)v0.z; hv[3] = (_Float16)v0.w;
    hv[4] = (_Float16)v1.x; hv[5] = (_Float16)v1.y; hv[6] = (_Float16)v1.z; hv[7] = (_Float16)v1.w;
    *(half8*)(xh + (size_t)o * 8) = hv;
  } else if (o < XH_JOBS + W1T_JOBS) {
    const int q = o - XH_JOBS;
    const int i = q >> 6, k0 = (q & 63) * 8;
#pragma unroll
    for (int j = 0; j < 8; ++j)
      W1T[(size_t)i * DIM + k0 + j] = (_Float16)W1[(size_t)(k0 + j) * INNER + i];
  } else if (o < PREP_JOBS) {
    const int q = o - XH_JOBS - W1T_JOBS;
    const int c = q >> 7, i0 = (q & 127) * 8;
#pragma unroll
    for (int j = 0; j < 8; ++j)
      W2T[(size_t)c * INNER + i0 + j] = (_Float16)W2[(size_t)(i0 + j) * (NC * NGRP) + c];
  }
}

// per-stage: each wave stages 4x 1KB (its two 16-row chunks of A and of B).
#define STAGE_P(bufbase, ks) do { \
    char* b_ = (bufbase); \
    GLOAD16(gA0 + (ks) * 32, b_ + (w * 2 + 0) * 1024); \
    GLOAD16(gA1 + (ks) * 32, b_ + (w * 2 + 1) * 1024); \
    GLOAD16(gB0 + (ks) * 32, b_ + 8192 + (w * 2 + 0) * 1024); \
    GLOAD16(gB1 + (ks) * 32, b_ + 8192 + (w * 2 + 1) * 1024); \
  } while (0)

// ================================================================ K1: GEMM1
// h = gelu(xh @ W1 + b1), fp16 [32768][1024]. 128x128, BK=32, 256 thr, 2-buf.
__global__ __launch_bounds__(256, 4)
void gemm1_kernel(const _Float16* __restrict__ xh, const _Float16* __restrict__ W1T,
                  const float* __restrict__ b1, _Float16* __restrict__ h) {
  __shared__ char smem[32768];
  const int tid = threadIdx.x;
  const int w = tid >> 6, l = tid & 63;
  const int l15 = l & 15, lq = l >> 4;
  const int bid = blockIdx.x;
  const int xcd = bid & 7, j = bid >> 3;            // 2048 = 8 * 256
  const int bm = xcd * 32 + (j >> 3), bn = j & 7;
  const int wm = w >> 1, wn = w & 1;

  const int r0 = (w * 2 + 0) * 16 + (l >> 2);
  const int r1 = (w * 2 + 1) * 16 + (l >> 2);
  const int c0 = (((l & 3) ^ (r0 & 3)) * 8);
  const int c1 = (((l & 3) ^ (r1 & 3)) * 8);
  const _Float16* gA0 = xh  + (size_t)(bm * 128 + r0) * DIM + c0;
  const _Float16* gA1 = xh  + (size_t)(bm * 128 + r1) * DIM + c1;
  const _Float16* gB0 = W1T + (size_t)(bn * 128 + r0) * DIM + c0;
  const _Float16* gB1 = W1T + (size_t)(bn * 128 + r1) * DIM + c1;

  f32x4 acc[4][4];
#pragma unroll
  for (int i = 0; i < 4; ++i)
#pragma unroll
    for (int jj = 0; jj < 4; ++jj) { f32x4 z = {0.f, 0.f, 0.f, 0.f}; acc[i][jj] = z; }

  const int swz = (lq ^ (l15 & 3)) << 4;
  const int aoff = (wm * 64 + l15) * 64 + swz;
  const int boff = 8192 + (wn * 64 + l15) * 64 + swz;

  STAGE_P(smem, 0);
  asm volatile("" ::: "memory");                    // pin issue order: S0 before S1
  STAGE_P(smem + 16384, 1);
  for (int ks = 0; ks < 16; ++ks) {
    if (ks + 1 < 16) PIPE_TOP(4); else PIPE_TOP(0); // S(ks) landed; S(ks+1) in flight
    const char* base = smem + (ks & 1) * 16384;
    half8 a[4], b[4];
#pragma unroll
    for (int mi = 0; mi < 4; ++mi) a[mi] = *(const half8*)(base + aoff + mi * 1024);
#pragma unroll
    for (int ni = 0; ni < 4; ++ni) b[ni] = *(const half8*)(base + boff + ni * 1024);
#pragma unroll
    for (int mi = 0; mi < 4; ++mi)
#pragma unroll
      for (int ni = 0; ni < 4; ++ni)
        acc[mi][ni] = __builtin_amdgcn_mfma_f32_16x16x32_f16(a[mi], b[ni], acc[mi][ni], 0, 0, 0);
    PIPE_BOT();                                     // all reads of buf[ks&1] done
    if (ks + 2 < 16) STAGE_P(smem + (ks & 1) * 16384, ks + 2);
  }
  asm volatile("s_waitcnt vmcnt(0) lgkmcnt(0)" ::: "memory");
  __syncthreads();

  // epilogue: +b1, GELU, fp16 -> eT (col XOR-swizzled by lq), coalesced store
  _Float16* eT = (_Float16*)smem;
  float bb[4];
#pragma unroll
  for (int ni = 0; ni < 4; ++ni) bb[ni] = b1[bn * 128 + wn * 64 + ni * 16 + l15];
#pragma unroll
  for (int mi = 0; mi < 4; ++mi) {
    const int row = wm * 64 + mi * 16 + lq * 4;
#pragma unroll
    for (int ni = 0; ni < 4; ++ni) {
      const int col = (wn * 64 + ni * 16 + l15) ^ (lq << 4);  // (row>>2)&3 == lq
#pragma unroll
      for (int r = 0; r < 4; ++r)
        eT[(row + r) * 128 + col] = (_Float16)gelu_f(acc[mi][ni][r] + bb[ni]);
    }
  }
  __syncthreads();
#pragma unroll
  for (int it = 0; it < 8; ++it) {
    const int s = tid + it * 256;
    const int row = s >> 4, i8 = s & 15;
    const int colp = (i8 * 8) ^ (((row >> 2) & 3) << 4);
    *(half8*)(h + (size_t)(bm * 128 + row) * INNER + bn * 128 + i8 * 8)
        = *(const half8*)(eT + row * 128 + colp);
  }
}

// ================================================================ K2: GEMM2
// logits = h @ W2 + b2 + gum; per-(token,slot) top-2 partials.
__global__ __launch_bounds__(256, 4)
void gemm2_kernel(const _Float16* __restrict__ h, const _Float16* __restrict__ W2T,
                  const float* __restrict__ b2, const float* __restrict__ gum,
                  unsigned* __restrict__ part) {
  __shared__ char smem[32768];
  const int tid = threadIdx.x;
  const int w = tid >> 6, l = tid & 63;
  const int l15 = l & 15, lq = l >> 4;
  const int bid = blockIdx.x;
  const int xcd = bid & 7, j = bid >> 3;            // 1280 = 8 * 160
  const int bm = xcd * 32 + j / 5, bt = j % 5;
  const int wm = w >> 1, wn = w & 1;

  const int r0 = (w * 2 + 0) * 16 + (l >> 2);
  const int r1 = (w * 2 + 1) * 16 + (l >> 2);
  const int c0 = (((l & 3) ^ (r0 & 3)) * 8);
  const int c1 = (((l & 3) ^ (r1 & 3)) * 8);
  const _Float16* gA0 = h   + (size_t)(bm * 128 + r0) * INNER + c0;
  const _Float16* gA1 = h   + (size_t)(bm * 128 + r1) * INNER + c1;
  const _Float16* gB0 = W2T + (size_t)(bt * 128 + r0) * INNER + c0;
  const _Float16* gB1 = W2T + (size_t)(bt * 128 + r1) * INNER + c1;

  f32x4 acc[4][4];
#pragma unroll
  for (int i = 0; i < 4; ++i)
#pragma unroll
    for (int jj = 0; jj < 4; ++jj) { f32x4 z = {0.f, 0.f, 0.f, 0.f}; acc[i][jj] = z; }

  const int swz = (lq ^ (l15 & 3)) << 4;
  const int aoff = (wm * 64 + l15) * 64 + swz;
  const int boff = 8192 + (wn * 64 + l15) * 64 + swz;

  STAGE_P(smem, 0);
  asm volatile("" ::: "memory");                    // pin issue order: S0 before S1
  STAGE_P(smem + 16384, 1);
  for (int ks = 0; ks < 32; ++ks) {
    if (ks + 1 < 32) PIPE_TOP(4); else PIPE_TOP(0);
    const char* base = smem + (ks & 1) * 16384;
    half8 a[4], b[4];
#pragma unroll
    for (int mi = 0; mi < 4; ++mi) a[mi] = *(const half8*)(base + aoff + mi * 1024);
#pragma unroll
    for (int ni = 0; ni < 4; ++ni) b[ni] = *(const half8*)(base + boff + ni * 1024);
#pragma unroll
    for (int mi = 0; mi < 4; ++mi)
#pragma unroll
      for (int ni = 0; ni < 4; ++ni)
        acc[mi][ni] = __builtin_amdgcn_mfma_f32_16x16x32_f16(a[mi], b[ni], acc[mi][ni], 0, 0, 0);
    PIPE_BOT();
    if (ks + 2 < 32) STAGE_P(smem + (ks & 1) * 16384, ks + 2);
  }
  asm volatile("s_waitcnt vmcnt(0) lgkmcnt(0)" ::: "memory");

  // epilogue in two halves (f32 eF[64][128], col XOR-swizzled by lq&1)
  float* eF = (float*)smem;
  const int nm = (bt == 2) ? 8 : 16;
#pragma unroll
  for (int half = 0; half < 2; ++half) {
    __syncthreads();
    if (wm == half) {
#pragma unroll
      for (int mi = 0; mi < 4; ++mi) {
        const int rl = mi * 16 + lq * 4;
#pragma unroll
        for (int ni = 0; ni < 4; ++ni) {
          const int col = (wn * 64 + ni * 16 + l15) ^ ((lq & 1) << 4);  // (rl>>2)&1 == lq&1
#pragma unroll
          for (int r = 0; r < 4; ++r) eF[(rl + r) * 128 + col] = acc[mi][ni][r];
        }
      }
    }
    __syncthreads();
#pragma unroll
    for (int it = 0; it < 8; ++it) {
      const int s = tid + it * 256;
      const int rl = s >> 5, cc = (s & 31) * 4;
      const int ccp = cc ^ (((rl >> 2) & 1) << 4);
      const int t = bm * 128 + half * 64 + rl;
      const float4 lv  = *(const float4*)(eF + rl * 128 + ccp);
      const float4 b2v = *(const float4*)(b2 + bt * 128 + cc);
      const float4 gv  = *(const float4*)(gum + (size_t)t * 640 + bt * 128 + cc);
      float m1 = -1e30f, m2 = -1e30f; unsigned i1 = 0;
      const float vv[4] = {(lv.x + b2v.x) + gv.x, (lv.y + b2v.y) + gv.y,
                           (lv.z + b2v.z) + gv.z, (lv.w + b2v.w) + gv.w};
#pragma unroll
      for (int r = 0; r < 4; ++r) {
        const unsigned c = (unsigned)(bt * 128 + cc + r);
        if (vv[r] > m1) { m2 = m1; m1 = vv[r]; i1 = c; }
        else if (vv[r] > m2) m2 = vv[r];
      }
      for (int m = 1; m <= nm; m <<= 1) {
        const float om1 = __shfl_xor(m1, m);
        const float om2 = __shfl_xor(m2, m);
        const unsigned oi = (unsigned)__shfl_xor((int)i1, m);
        const bool take = (om1 > m1) || (om1 == m1 && oi < i1);
        if (take) { m2 = fmaxf(m1, om2); m1 = om1; i1 = oi; }
        else      { m2 = fmaxf(m2, om1); }
      }
      const int lr = tid & 31;
      const bool writer = (bt == 2) ? (lr == 0 || lr == 16) : (lr == 0);
      if (writer) {
        int slot;
        if (bt == 0) slot = 0; else if (bt == 1) slot = 1;
        else if (bt == 3) slot = 4; else if (bt == 4) slot = 5;
        else slot = (i1 < (unsigned)NC) ? 2 : 3;
        const unsigned ing = (i1 < (unsigned)NC) ? i1 : (i1 - NC);
        unsigned* p = part + ((size_t)t * 6 + slot) * 4;
        p[0] = __float_as_uint(m1);
        p[1] = __float_as_uint(m2);
        p[2] = ing;
      }
    }
  }
}

// ================================================================ K3: combine + gather
__global__ __launch_bounds__(256, 4)
void reduce_kernel(const unsigned* __restrict__ part, const float* __restrict__ emb,
                   float* __restrict__ out, unsigned* __restrict__ cnt,
                   unsigned* __restrict__ list) {
  __shared__ unsigned idxs[256];
  const int tid = threadIdx.x;
  const int pair = blockIdx.x * 256 + tid;
  const int t = pair >> 1, g = pair & 1;
  float m1 = -1e30f, m2 = -1e30f; unsigned i1 = 0;
#pragma unroll
  for (int s = 0; s < 3; ++s) {
    const unsigned* p = part + ((size_t)t * 6 + g * 3 + s) * 4;
    const float a1 = __uint_as_float(p[0]);
    const float a2 = __uint_as_float(p[1]);
    const unsigned ai = p[2];
    if (a1 > m1) { m2 = fmaxf(m1, a2); m1 = a1; i1 = ai; }
    else         { m2 = fmaxf(m2, a1); }
  }
  idxs[tid] = i1;
  if (m1 - m2 < MARGIN) {
    const unsigned pos = atomicAdd(cnt, 1u);
    if (pos < RCAP) list[pos] = (unsigned)((t << 1) | g);
  }
  __syncthreads();
#pragma unroll
  for (int it = 0; it < 32; ++it) {
    const int s2 = tid + it * 256;
    const int p = s2 >> 5, dd = (s2 & 31) * 4;
    *(float4*)(out + (size_t)blockIdx.x * 32768 + p * 128 + dd)
        = *(const float4*)(emb + (size_t)idxs[p] * VD + dd);
  }
}

// ================================================================ refine (unchanged)
__global__ __launch_bounds__(512, 4)
void refine1_kernel(const float* __restrict__ x, const float* __restrict__ W1,
                    const float* __restrict__ b1,
                    const unsigned* __restrict__ cnt, const unsigned* __restrict__ list,
                    float* __restrict__ hdws) {
  __shared__ float xs[DIM];
  unsigned n = cnt[0]; if (n > RCAP) n = RCAP;
  const unsigned e = blockIdx.x;
  if (e >= n) return;
  const unsigned tok = list[e] >> 1;
  const int tid = threadIdx.x;
  xs[tid] = x[(size_t)tok * DIM + tid];
  __syncthreads();
  double a0 = 0.0, a1 = 0.0, c0 = 0.0, c1 = 0.0;
#pragma unroll 4
  for (int k = 0; k < DIM; k += 2) {
    const double x0 = (double)xs[k], x1 = (double)xs[k + 1];
    const float* rr0 = W1 + (size_t)k * INNER + tid;
    const float* rr1 = W1 + (size_t)(k + 1) * INNER + tid;
    a0 += x0 * (double)rr0[0];
    a1 += x0 * (double)rr0[512];
    c0 += x1 * (double)rr1[0];
    c1 += x1 * (double)rr1[512];
  }
  const double s0 = a0 + c0 + (double)b1[tid];
  const double s1 = a1 + c1 + (double)b1[tid + 512];
  hdws[(size_t)e * INNER + tid]       = (float)(0.5 * s0 * (1.0 + erf(s0 * 0.70710678118654752440)));
  hdws[(size_t)e * INNER + tid + 512] = (float)(0.5 * s1 * (1.0 + erf(s1 * 0.70710678118654752440)));
}

__global__ __launch_bounds__(320, 4)
void refine2_kernel(const float* __restrict__ gum, const float* __restrict__ W2,
                    const float* __restrict__ b2, const float* __restrict__ emb,
                    float* __restrict__ out,
                    const unsigned* __restrict__ cnt, const unsigned* __restrict__ list,
                    const float* __restrict__ hdws) {
  __shared__ float hs[INNER];
  __shared__ double wv[5];
  __shared__ int wi[5];
  __shared__ int best;
  unsigned n = cnt[0]; if (n > RCAP) n = RCAP;
  const unsigned e = blockIdx.x;
  if (e >= n) return;
  const unsigned tok = list[e] >> 1;
  const int g = (int)(list[e] & 1u);
  const int tid = threadIdx.x;
  for (int j = tid; j < INNER; j += 320) hs[j] = hdws[(size_t)e * INNER + j];
  __syncthreads();
  const float* w2c = W2 + (size_t)g * NC + tid;
  double acc = 0.0, accb = 0.0;
#pragma unroll 4
  for (int k = 0; k < INNER; k += 2) {
    acc  += (double)hs[k]     * (double)w2c[(size_t)k * (NC * NGRP)];
    accb += (double)hs[k + 1] * (double)w2c[(size_t)(k + 1) * (NC * NGRP)];
  }
  double v = acc + accb + (double)b2[g * NC + tid]
                        + (double)gum[((size_t)tok * 2 + g) * NC + tid];
  int bi = tid;
#pragma unroll
  for (int m = 1; m < 64; m <<= 1) {
    const double ov = __shfl_xor(v, m);
    const int oi = __shfl_xor(bi, m);
    if (ov > v || (ov == v && oi < bi)) { v = ov; bi = oi; }
  }
  if ((tid & 63) == 0) { wv[tid >> 6] = v; wi[tid >> 6] = bi; }
  __syncthreads();
  if (tid == 0) {
    double bv = wv[0]; int bb = wi[0];
#pragma unroll
    for (int k = 1; k < 5; ++k)
      if (wv[k] > bv || (wv[k] == bv && wi[k] < bb)) { bv = wv[k]; bb = wi[k]; }
    best = bb;
  }
  __syncthreads();
  if (tid < VD)
    out[(size_t)tok * OUTD + g * VD + tid] = emb[(size_t)best * VD + tid];
}

// ================================================================ FALLBACK (R5 path)
#define W1F_N (16 * 64 * 64)
#define W2F_N (32 * 40 * 64)
__global__ void prep_kernel(const float* __restrict__ W1, const float* __restrict__ W2,
                            _Float16* __restrict__ W1F, _Float16* __restrict__ W2F,
                            unsigned* __restrict__ cnt) {
  const int o = blockIdx.x * 256 + threadIdx.x;
  if (o == 0) cnt[0] = 0u;
  if (o < W1F_N) {
    const int l = o & 63, ib = (o >> 6) & 63, ks = o >> 12;
    const int inner = ib * 16 + (l & 15);
    const int kb = ks * 32 + (l >> 4) * 8;
    _Float16* d = W1F + (size_t)o * 8;
#pragma unroll
    for (int j = 0; j < 8; ++j) d[j] = (_Float16)W1[(size_t)(kb + j) * INNER + inner];
  } else {
    const int o2 = o - W1F_N;
    if (o2 < W2F_N) {
      const int l = o2 & 63, cb = (o2 >> 6) % 40, ks = o2 / (40 * 64);
      const int code = cb * 16 + (l & 15);
      const int kb = ks * 32 + (l >> 4) * 8;
      _Float16* d = W2F + (size_t)o2 * 8;
#pragma unroll
      for (int j = 0; j < 8; ++j) d[j] = (_Float16)W2[(size_t)(kb + j) * (NC * NGRP) + code];
    }
  }
}

__global__ __launch_bounds__(512, 4)
void fused_kernel(const float* __restrict__ x, const float* __restrict__ gum,
                  const _Float16* __restrict__ W1F, const _Float16* __restrict__ W2F,
                  const float* __restrict__ b1, const float* __restrict__ b2,
                  const float* __restrict__ emb, float* __restrict__ out,
                  unsigned* __restrict__ cnt, unsigned* __restrict__ list) {
  extern __shared__ char smem[];
  float*    redm1 = (float*)(smem + 65536);
  float*    redm2 = (float*)(smem + 65536 + 1024);
  unsigned* redi  = (unsigned*)(smem + 65536 + 2048);
  unsigned* idxs  = (unsigned*)(smem + 65536 + 3072);
  const int tid = threadIdx.x;
  const int w = tid >> 6, l = tid & 63;
  const int l15 = l & 15, lq = l >> 4;
  const int T0 = blockIdx.x << 5;
#pragma unroll
  for (int i = 0; i < 8; ++i) {
    const int q = tid + i * 512;
    const int row = q >> 7;
    const int c = (q & 127) << 2;
    const float4 v = *(const float4*)(x + (size_t)(T0 + row) * DIM + c);
    half4 hv; hv[0] = (_Float16)v.x; hv[1] = (_Float16)v.y;
    hv[2] = (_Float16)v.z; hv[3] = (_Float16)v.w;
    const unsigned byte = ((unsigned)(row * 1024 + c * 2)) ^ ((unsigned)(row & 7) << 4);
    *(half4*)(smem + byte) = hv;
  }
  __syncthreads();
  {
    f32x4 acc[8][2];
#pragma unroll
    for (int i = 0; i < 8; ++i)
#pragma unroll
      for (int jj = 0; jj < 2; ++jj) { f32x4 z = {0.f,0.f,0.f,0.f}; acc[i][jj] = z; }
    const _Float16* w1f = W1F + (size_t)(w * 8) * 512 + (size_t)l * 8;
    for (int ks = 0; ks < 16; ++ks) {
      const int k0 = ks * 32;
      half8 a[8], bf[2];
#pragma unroll
      for (int mt = 0; mt < 8; ++mt) a[mt] = *(const half8*)(w1f + (size_t)(ks * 64 + mt) * 512);
#pragma unroll
      for (int nt = 0; nt < 2; ++nt) {
        const int token = nt * 16 + l15;
        const unsigned byte = ((unsigned)(token * 1024 + (k0 + lq * 8) * 2))
                              ^ ((unsigned)(token & 7) << 4);
        bf[nt] = *(const half8*)(smem + byte);
      }
#pragma unroll
      for (int mt = 0; mt < 8; ++mt)
#pragma unroll
        for (int nt = 0; nt < 2; ++nt)
          acc[mt][nt] = __builtin_amdgcn_mfma_f32_16x16x32_f16(a[mt], bf[nt], acc[mt][nt], 0, 0, 0);
    }
    __syncthreads();
#pragma unroll
    for (int mt = 0; mt < 8; ++mt) {
      const int inner0 = w * 128 + mt * 16 + lq * 4;
      const float4 bv = *(const float4*)(b1 + inner0);
#pragma unroll
      for (int nt = 0; nt < 2; ++nt) {
        const int token = nt * 16 + l15;
        const f32x4 v = acc[mt][nt];
        half4 hv;
        hv[0] = (_Float16)gelu_f(v[0] + bv.x);
        hv[1] = (_Float16)gelu_f(v[1] + bv.y);
        hv[2] = (_Float16)gelu_f(v[2] + bv.z);
        hv[3] = (_Float16)gelu_f(v[3] + bv.w);
        const unsigned byte = ((unsigned)(token * 2048 + inner0 * 2))
                              ^ ((unsigned)(token & 7) << 4);
        *(half4*)(smem + byte) = hv;
      }
    }
  }
  __syncthreads();
  const int g = w >> 2;
  {
    f32x4 acc[5][2];
#pragma unroll
    for (int i = 0; i < 5; ++i)
#pragma unroll
      for (int jj = 0; jj < 2; ++jj) { f32x4 z = {0.f,0.f,0.f,0.f}; acc[i][jj] = z; }
    const _Float16* w2f = W2F + (size_t)(w * 5) * 512 + (size_t)l * 8;
    for (int ks = 0; ks < 32; ++ks) {
      const int k0 = ks * 32;
      half8 a[5], bf[2];
#pragma unroll
      for (int mt = 0; mt < 5; ++mt) a[mt] = *(const half8*)(w2f + (size_t)(ks * 40 + mt) * 512);
#pragma unroll
      for (int nt = 0; nt < 2; ++nt) {
        const int token = nt * 16 + l15;
        const unsigned byte = ((unsigned)(token * 2048 + (k0 + lq * 8) * 2))
                              ^ ((unsigned)(token & 7) << 4);
        bf[nt] = *(const half8*)(smem + byte);
      }
#pragma unroll
      for (int mt = 0; mt < 5; ++mt)
#pragma unroll
        for (int nt = 0; nt < 2; ++nt)
          acc[mt][nt] = __builtin_amdgcn_mfma_f32_16x16x32_f16(a[mt], bf[nt], acc[mt][nt], 0, 0, 0);
    }
    float m1v[2] = {-1e30f,-1e30f};
    float m2v[2] = {-1e30f,-1e30f};
    unsigned i1v[2] = {0,0};
#pragma unroll
    for (int mt = 0; mt < 5; ++mt) {
      const int code0 = w * 80 + mt * 16 + lq * 4;
      const int cg0 = code0 - g * NC;
      const float4 b2v = *(const float4*)(b2 + code0);
#pragma unroll
      for (int nt = 0; nt < 2; ++nt) {
        const int tokg = T0 + nt * 16 + l15;
        const float4 gv = *(const float4*)(gum + ((size_t)tokg * 2 + g) * NC + cg0);
        const f32x4 v = acc[mt][nt];
        const float ss[4] = {v[0] + b2v.x + gv.x, v[1] + b2v.y + gv.y,
                             v[2] + b2v.z + gv.z, v[3] + b2v.w + gv.w};
#pragma unroll
        for (int r = 0; r < 4; ++r) {
          const float sv = ss[r];
          const unsigned cc = (unsigned)(cg0 + r);
          if (sv > m1v[nt]) { m2v[nt] = m1v[nt]; m1v[nt] = sv; i1v[nt] = cc; }
          else if (sv > m2v[nt]) m2v[nt] = sv;
        }
      }
    }
#pragma unroll
    for (int mask = 16; mask <= 32; mask <<= 1) {
#pragma unroll
      for (int nt = 0; nt < 2; ++nt) {
        const float om1 = __shfl_xor(m1v[nt], mask);
        const float om2 = __shfl_xor(m2v[nt], mask);
        const unsigned oi = (unsigned)__shfl_xor((int)i1v[nt], mask);
        const bool take = (om1 > m1v[nt]) || (om1 == m1v[nt] && oi < i1v[nt]);
        if (take) { m2v[nt] = fmaxf(m1v[nt], om2); m1v[nt] = om1; i1v[nt] = oi; }
        else      { m2v[nt] = fmaxf(m2v[nt], om1); }
      }
    }
    if (l < 16) {
#pragma unroll
      for (int nt = 0; nt < 2; ++nt) {
        const int tok = nt * 16 + l15;
        redm1[w * 32 + tok] = m1v[nt];
        redm2[w * 32 + tok] = m2v[nt];
        redi [w * 32 + tok] = i1v[nt];
      }
    }
  }
  __syncthreads();
  if (tid < 64) {
    const int pg = tid >> 5;
    const int tok = tid & 31;
    float m1 = -1e30f, m2 = -1e30f; unsigned i1 = 0;
#pragma unroll
    for (int k = 0; k < 4; ++k) {
      const int ww = pg * 4 + k;
      const float a1 = redm1[ww * 32 + tok];
      const float a2 = redm2[ww * 32 + tok];
      const unsigned ai = redi[ww * 32 + tok];
      if (a1 > m1) { m2 = fmaxf(m1, a2); m1 = a1; i1 = ai; }
      else         { m2 = fmaxf(m2, a1); }
    }
    idxs[tid] = i1;
    if (m1 - m2 < MARGIN) {
      const unsigned pos = atomicAdd(cnt, 1u);
      if (pos < RCAP) list[pos] = (unsigned)(((T0 + tok) << 1) | pg);
    }
  }
  __syncthreads();
#pragma unroll
  for (int i = 0; i < 4; ++i) {
    const int q = tid + i * 512;
    const int p = q >> 5;
    const int dd = q & 31;
    const int pg = p >> 5;
    const int tok = p & 31;
    const unsigned idx = idxs[p];
    *(float4*)(out + (size_t)(T0 + tok) * OUTD + pg * VD + dd * 4)
      = *(const float4*)(emb + (size_t)idx * VD + dd * 4);
  }
}

__global__ __launch_bounds__(512, 1)
void refine_kernel(const float* __restrict__ x, const float* __restrict__ gum,
                   const float* __restrict__ W1, const float* __restrict__ b1,
                   const float* __restrict__ W2, const float* __restrict__ b2,
                   const float* __restrict__ emb, float* __restrict__ out,
                   const unsigned* __restrict__ cnt, const unsigned* __restrict__ list) {
  __shared__ double xs[4][DIM];
  __shared__ double hd[4][INNER];
  __shared__ double sc[4][NC];
  __shared__ int amax[4];
  const int tid = threadIdx.x;
  unsigned n = cnt[0];
  if (n > RCAP) n = RCAP;
  for (unsigned base = blockIdx.x * 4u; base < n; base += gridDim.x * 4u) {
    const int nb = (int)((n - base) < 4u ? (n - base) : 4u);
    unsigned ng[4];
#pragma unroll
    for (int e = 0; e < 4; ++e) ng[e] = list[base + (e < nb ? e : 0)];
    for (int e = 0; e < nb; ++e)
      xs[e][tid] = (double)x[(size_t)(ng[e] >> 1) * DIM + tid];
    __syncthreads();
#pragma unroll
    for (int jj = 0; jj < 2; ++jj) {
      const int j = tid + jj * 512;
      double a0 = 0, a1 = 0, a2 = 0, a3 = 0;
      for (int k = 0; k < DIM; ++k) {
        const double wvv = (double)W1[(size_t)k * INNER + j];
        a0 += xs[0][k] * wvv; a1 += xs[1][k] * wvv;
        a2 += xs[2][k] * wvv; a3 += xs[3][k] * wvv;
      }
      const double bb = (double)b1[j];
      const double s0 = a0 + bb, s1 = a1 + bb, s2 = a2 + bb, s3 = a3 + bb;
      hd[0][j] = 0.5 * s0 * (1.0 + erf(s0 * 0.70710678118654752440));
      hd[1][j] = 0.5 * s1 * (1.0 + erf(s1 * 0.70710678118654752440));
      hd[2][j] = 0.5 * s2 * (1.0 + erf(s2 * 0.70710678118654752440));
      hd[3][j] = 0.5 * s3 * (1.0 + erf(s3 * 0.70710678118654752440));
    }
    __syncthreads();
    for (int task = tid; task < 4 * NC; task += 512) {
      const int e = task / NC;
      const int c = task - e * NC;
      if (e < nb) {
        const unsigned tok = ng[e] >> 1;
        const int gg = (int)(ng[e] & 1u);
        const float* w2c = W2 + (size_t)gg * NC + c;
        double acc = 0.0;
        for (int k = 0; k < INNER; ++k)
          acc += hd[e][k] * (double)w2c[(size_t)k * (NC * NGRP)];
        sc[e][c] = acc + (double)b2[gg * NC + c]
                       + (double)gum[((size_t)tok * 2 + gg) * NC + c];
      }
    }
    __syncthreads();
    if (tid < 4 && tid < nb) {
      double bestv = sc[tid][0]; int bi = 0;
      for (int c = 1; c < NC; ++c)
        if (sc[tid][c] > bestv) { bestv = sc[tid][c]; bi = c; }
      amax[tid] = bi;
    }
    __syncthreads();
    {
      const int e = tid >> 7;
      const int d = tid & 127;
      if (e < nb) {
        const unsigned tok = ng[e] >> 1;
        const int gg = (int)(ng[e] & 1u);
        out[(size_t)tok * OUTD + gg * VD + d] = emb[(size_t)amax[e] * VD + d];
      }
    }
    __syncthreads();
  }
}

// ================================================================ launch
extern "C" void kernel_launch(void* const* d_in, const int* in_sizes, int n_in,
                              void* d_out, int out_size, void* d_ws, size_t ws_size,
                              hipStream_t stream) {
  (void)in_sizes; (void)n_in; (void)out_size;
  const float* x   = (const float*)d_in[0];
  const float* gum = (const float*)d_in[1];
  const float* W1  = (const float*)d_in[2];
  const float* b1  = (const float*)d_in[3];
  const float* W2  = (const float*)d_in[4];
  const float* b2  = (const float*)d_in[5];
  const float* emb = (const float*)d_in[6];
  float* out = (float*)d_out;
  char* ws = (char*)d_ws;
  unsigned* cnt  = (unsigned*)ws;
  unsigned* list = (unsigned*)(ws + L_LIST);

  if (ws_size >= (size_t)WS_NEED) {
    _Float16* W1T = (_Float16*)(ws + L_W1T);
    _Float16* W2T = (_Float16*)(ws + L_W2T);
    _Float16* xh  = (_Float16*)(ws + L_XH);
    _Float16* h   = (_Float16*)(ws + L_H);
    unsigned* part = (unsigned*)(ws + L_PART);
    float* hdws = (float*)(ws + L_HDW);

    prep2_kernel<<<(PREP_JOBS + 255) / 256, 256, 0, stream>>>(x, W1, W2, xh, W1T, W2T, cnt);
    gemm1_kernel<<<(NTOK / 128) * 8, 256, 0, stream>>>(xh, W1T, b1, h);
    gemm2_kernel<<<(NTOK / 128) * 5, 256, 0, stream>>>(h, W2T, b2, gum, part);
    reduce_kernel<<<NTOK * NGRP / 256, 256, 0, stream>>>(part, emb, out, cnt, list);
    refine1_kernel<<<RCAP, 512, 0, stream>>>(x, W1, b1, cnt, list, hdws);
    refine2_kernel<<<RCAP, 320, 0, stream>>>(gum, W2, b2, emb, out, cnt, list, hdws);
  } else {
    _Float16* W1F = (_Float16*)(ws + W1F_OFF);
    _Float16* W2F = (_Float16*)(ws + W2F_OFF);
    hipFuncSetAttribute((const void*)fused_kernel,
                        hipFuncAttributeMaxDynamicSharedMemorySize, SMEM_BYTES);
    const int prep_items = W1F_N + W2F_N;
    prep_kernel<<<(prep_items + 255) / 256, 256, 0, stream>>>(W1, W2, W1F, W2F, cnt);
    fused_kernel<<<NTOK / 32, 512, SMEM_BYTES, stream>>>(x, gum, W1F, W2F, b1, b2,
                                                         emb, out, cnt, list);
    refine_kernel<<<256, 512, 0, stream>>>(x, gum, W1, b1, W2, b2, emb, out, cnt, list);
  }
}